// Round 3
// baseline (250.494 us; speedup 1.0000x reference)
//
#include <hip/hip_runtime.h>
#include <cstdint>

// ---------------- ws layout (bytes) ----------------
// pw      @ 0        : 896 uint32 packed weight bits (atomicOr-built; memset first)
// fc1_wT  @ 4096     : [800][256] f32 (zero-padded k>=784)   819200 B
// fc2_wT  @ 823296   : [256][128] f32                        131072 B
// h3T     @ 954368   : [800][4096] f32 (rows>=784 zeroed)  13107200 B
// h1T     @ 14061568 : [256][4096] f32                      4194304 B
// h2T     @ 18255872 : [128][4096] f32                      2097152 B
#define OFF_PW    0
#define OFF_W1T   4096
#define OFF_W2T   823296
#define OFF_H3T   954368
#define OFF_H1T   14061568
#define OFF_H2T   18255872

// ---------------- prep: flat one-element-per-thread, atomicOr packing -------
__global__ __launch_bounds__(256) void prep(
    const float* __restrict__ w1, const float* __restrict__ w2,
    const float* __restrict__ w3,
    const float* __restrict__ fc1_w, const float* __restrict__ fc2_w,
    uint32_t* __restrict__ pw, float* __restrict__ w1T,
    float* __restrict__ w2T, float* __restrict__ h3T) {
    int idx = blockIdx.x * 256 + threadIdx.x;
    if (idx < 204800) {               // fc1_wT [800][256]
        int k = idx >> 8, n = idx & 255;
        w1T[idx] = (k < 784) ? fc1_w[n * 784 + k] : 0.f;
        return;
    }
    idx -= 204800;
    if (idx < 32768) {                // fc2_wT [256][128]
        int k = idx >> 7, n = idx & 127;
        w2T[idx] = fc2_w[n * 256 + k];
        return;
    }
    idx -= 32768;
    if (idx < 65536) {                // zero h3T pad rows 784..799
        h3T[784 * 4096 + idx] = 0.f;
        return;
    }
    idx -= 65536;
    if (idx < 288) {                  // w1 bits: pw[c] bit tap
        int c = idx / 9, tap = idx - c * 9;
        if (w1[idx] > 0.f) atomicOr(&pw[c], 1u << tap);
        return;
    }
    idx -= 288;
    if (idx < 18432) {                // w2 bits: pw[32+oc*9+tap] bit ic
        int oc = idx / 288, r = idx - oc * 288;
        int ic = r / 9, tap = r - ic * 9;
        if (w2[idx] > 0.f) atomicOr(&pw[32 + oc * 9 + tap], 1u << ic);
        return;
    }
    idx -= 18432;
    if (idx < 9216) {                 // w3 bits: pw[608+oc*18+tap*2+(ic>>5)]
        int oc = idx / 576, r = idx - oc * 576;
        int ic = r / 9, tap = r - ic * 9;
        if (w3[idx] > 0.f)
            atomicOr(&pw[608 + oc * 18 + tap * 2 + (ic >> 5)], 1u << (ic & 31));
    }
}

__device__ __forceinline__ uint32_t bfe3(uint32_t r, int j) {
    return (r >> j) & 7u;
}

// ---------------- conv stack: one image per block, xnor-popcount ------------
__global__ __launch_bounds__(256, 4) void conv_stack(
    const float* __restrict__ x, const float* __restrict__ b1,
    const float* __restrict__ b2, const float* __restrict__ b3,
    const uint32_t* __restrict__ pw, float* __restrict__ h3T) {
    __shared__ uint32_t s_w1[32];
    __shared__ int s_ic1[32];
    __shared__ int s_ic2[64];
    __shared__ uint32_t s_c2[128];    // per-oc border corr bytes (2 words)
    __shared__ uint32_t s_c3[32];
    __shared__ uint32_t s_W2p[768];   // [oc*12 + tap], padded to 12
    __shared__ uint32_t s_W3[288];    // [oc*18 + tap*2 + w]
    __shared__ float s_b3[16];
    __shared__ uint32_t s_xr[28];     // pre-shifted (<<1) padded row bits
    __shared__ uint32_t s_H1[256];    // padded 16x16
    __shared__ uint32_t s_H2[162];    // padded 9x9 x2

    const int t = threadIdx.x;
    const int img = blockIdx.x;

    s_H1[t] = 0;
    if (t < 162) s_H2[t] = 0;
    if (t < 28) {
        const float4* xr = (const float4*)(x + img * 784 + t * 28);
        uint32_t b = 0;
#pragma unroll
        for (int q = 0; q < 7; ++q) {
            float4 v = xr[q];
            b |= (v.x > 0.f ? 1u : 0u) << (q * 4 + 0);
            b |= (v.y > 0.f ? 1u : 0u) << (q * 4 + 1);
            b |= (v.z > 0.f ? 1u : 0u) << (q * 4 + 2);
            b |= (v.w > 0.f ? 1u : 0u) << (q * 4 + 3);
        }
        s_xr[t] = b << 1;             // pad col -1 at bit 0
    }
    if (t >= 32 && t < 64) {
        int c = t - 32;
        s_w1[c] = pw[c];
        s_ic1[c] = (int)floorf(-b1[c]) + 1;
    }
    if (t >= 64 && t < 128) {         // conv2 corr tables from packed bits
        int oc = t - 64;
        s_ic2[oc] = (int)floorf(-b2[oc]) + 1;
        int p[9];
#pragma unroll
        for (int k = 0; k < 9; ++k) p[k] = __popc(pw[32 + oc * 9 + k]);
        s_c2[oc * 2] = (uint32_t)(p[0] + p[1] + p[2]) |
                       ((uint32_t)(p[6] + p[7] + p[8]) << 8) |
                       ((uint32_t)(p[0] + p[3] + p[6]) << 16) |
                       ((uint32_t)(p[2] + p[5] + p[8]) << 24);
        s_c2[oc * 2 + 1] = (uint32_t)p[0] | ((uint32_t)p[2] << 8) |
                           ((uint32_t)p[6] << 16) | ((uint32_t)p[8] << 24);
    }
    if (t >= 128 && t < 144) {        // conv3 corr tables
        int oc = t - 128;
        s_b3[oc] = b3[oc];
        int p[9];
#pragma unroll
        for (int k = 0; k < 9; ++k)
            p[k] = __popc(pw[608 + oc * 18 + k * 2]) +
                   __popc(pw[608 + oc * 18 + k * 2 + 1]);
        s_c3[oc * 2] = (uint32_t)(p[0] + p[1] + p[2]) |
                       ((uint32_t)(p[6] + p[7] + p[8]) << 8) |
                       ((uint32_t)(p[0] + p[3] + p[6]) << 16) |
                       ((uint32_t)(p[2] + p[5] + p[8]) << 24);
        s_c3[oc * 2 + 1] = (uint32_t)p[0] | ((uint32_t)p[2] << 8) |
                           ((uint32_t)p[6] << 16) | ((uint32_t)p[8] << 24);
    }
    for (int i = t; i < 768; i += 256) {
        int oc = i / 12, tap = i - oc * 12;
        s_W2p[i] = (tap < 9) ? pw[32 + oc * 9 + tap] : 0u;
    }
    for (int i = t; i < 288; i += 256) s_W3[i] = pw[608 + i];
    __syncthreads();

    // ---- conv1 (1->32) + pool + binarize: 196 threads, interior-first ----
    if (t < 196) {
        int pi, pj;
        if (t < 144) { pi = 1 + t / 12; pj = 1 + t % 12; }
        else {
            int b = t - 144;
            if (b < 14)      { pi = 0;  pj = b; }
            else if (b < 28) { pi = 13; pj = b - 14; }
            else if (b < 40) { pi = 1 + (b - 28); pj = 0; }
            else             { pi = 1 + (b - 40); pj = 13; }
        }
        uint32_t r[4];
#pragma unroll
        for (int k = 0; k < 4; ++k) {
            int y = 2 * pi - 1 + k;
            r[k] = ((unsigned)y < 28u) ? s_xr[y] : 0u;
        }
        uint32_t samp[4];
#pragma unroll
        for (int a = 0; a < 2; ++a)
#pragma unroll
            for (int bb = 0; bb < 2; ++bb) {
                int j = 2 * pj + bb;
                samp[a * 2 + bb] = bfe3(r[a], j) | (bfe3(r[a + 1], j) << 3) |
                                   (bfe3(r[a + 2], j) << 6);
            }
        uint32_t word = 0;
        if (t < 144) {
#pragma unroll 4
            for (int c = 0; c < 32; ++c) {
                uint32_t w = s_w1[c];
                int S = __popc(samp[0] ^ w);
                int S1 = __popc(samp[1] ^ w); S = S1 < S ? S1 : S;
                int S2 = __popc(samp[2] ^ w); S = S2 < S ? S2 : S;
                int S3 = __popc(samp[3] ^ w); S = S3 < S ? S3 : S;
                word |= (uint32_t)(9 - 2 * S >= s_ic1[c]) << c;
            }
        } else {
            uint32_t inv[4];
            int Nv[4];
#pragma unroll
            for (int a = 0; a < 2; ++a)
#pragma unroll
                for (int bb = 0; bb < 2; ++bb) {
                    int i = 2 * pi + a, j = 2 * pj + bb;
                    inv[a * 2 + bb] =
                        (i == 0 ? 0x7u : 0u) | (i == 27 ? 0x1C0u : 0u) |
                        (j == 0 ? 0x49u : 0u) | (j == 27 ? 0x124u : 0u);
                }
#pragma unroll
            for (int p = 0; p < 4; ++p) Nv[p] = 9 - __popc(inv[p]);
#pragma unroll 4
            for (int c = 0; c < 32; ++c) {
                uint32_t w = s_w1[c];
                int vmax = -100;
#pragma unroll
                for (int p = 0; p < 4; ++p) {
                    int v = Nv[p] - 2 * (__popc(samp[p] ^ w) - __popc(w & inv[p]));
                    vmax = v > vmax ? v : vmax;
                }
                word |= (uint32_t)(vmax >= s_ic1[c]) << c;
            }
        }
        s_H1[(pi + 1) * 16 + pj + 1] = word;
    }
    __syncthreads();

    // ---- conv2 (32->64) + pool + binarize: 245 threads = 49 pos x 5 grps ----
    if (t < 245) {
        int pos = t / 5, grp = t - pos * 5;
        int pi, pj;
        if (pos < 25) { pi = 1 + pos / 5; pj = 1 + pos % 5; }
        else {
            int b = pos - 25;
            if (b < 7)       { pi = 0; pj = b; }
            else if (b < 14) { pi = 6; pj = b - 7; }
            else if (b < 19) { pi = b - 13; pj = 0; }
            else             { pi = b - 18; pj = 6; }
        }
        uint32_t cell[16];
#pragma unroll
        for (int r = 0; r < 4; ++r)
#pragma unroll
            for (int c = 0; c < 4; ++c)
                cell[r * 4 + c] = s_H1[(2 * pi + r) * 16 + (2 * pj + c)];
        const bool border = pos >= 25;
        int rsh = (pi == 6) ? 8 : 0;
        uint32_t mR = (pi == 0) ? 0x3u : ((pi == 6) ? 0xCu : 0u);
        int csh = (pj == 6) ? 24 : 16;
        uint32_t mC = (pj == 0) ? 0x5u : ((pj == 6) ? 0xAu : 0u);
        int pcell = ((pi == 6) ? 2 : 0) + ((pj == 6) ? 1 : 0);
        int psh = pcell * 8;
        uint32_t mP = (mR && mC) ? (1u << pcell) : 0u;
        int Nv[4];
#pragma unroll
        for (int p = 0; p < 4; ++p) {
            int rP = (mR >> p) & 1, cP = (mC >> p) & 1;
            Nv[p] = 32 * (9 - 3 * rP - 3 * cP + (rP & cP));
        }
        int ocs = grp * 13;
        int cnt = (grp < 4) ? 13 : 12;
        uint32_t lo = 0, hi = 0;
        for (int oi = 0; oi < cnt; ++oi) {
            int oc = ocs + oi;
            const uint32_t* wp = &s_W2p[oc * 12];
            uint4 wA = *(const uint4*)wp;
            uint4 wB = *(const uint4*)(wp + 4);
            uint32_t w8 = wp[8];
            uint32_t w[9] = {wA.x, wA.y, wA.z, wA.w, wB.x, wB.y, wB.z, wB.w, w8};
            int S[4];
#pragma unroll
            for (int a = 0; a < 2; ++a)
#pragma unroll
                for (int bb = 0; bb < 2; ++bb) {
                    int acc = 0;
#pragma unroll
                    for (int kh = 0; kh < 3; ++kh)
#pragma unroll
                        for (int kw = 0; kw < 3; ++kw)
                            acc += __popc(cell[(a + kh) * 4 + (bb + kw)] ^ w[kh * 3 + kw]);
                    S[a * 2 + bb] = acc;
                }
            int bitv;
            if (!border) {
                int Sm = S[0];
                Sm = S[1] < Sm ? S[1] : Sm;
                Sm = S[2] < Sm ? S[2] : Sm;
                Sm = S[3] < Sm ? S[3] : Sm;
                bitv = (288 - 2 * Sm >= s_ic2[oc]) ? 1 : 0;
            } else {
                uint32_t cw0 = s_c2[oc * 2], cw1 = s_c2[oc * 2 + 1];
                int rB = (cw0 >> rsh) & 0xFF;
                int cB = (cw0 >> csh) & 0xFF;
                int pB = (cw1 >> psh) & 0xFF;
                int vmax = -100000;
#pragma unroll
                for (int p = 0; p < 4; ++p) {
                    int corr = (((mR >> p) & 1) ? rB : 0) +
                               (((mC >> p) & 1) ? cB : 0) -
                               (((mP >> p) & 1) ? pB : 0);
                    int v = Nv[p] - 2 * (S[p] - corr);
                    vmax = v > vmax ? v : vmax;
                }
                bitv = (vmax >= s_ic2[oc]) ? 1 : 0;
            }
            if (oc < 32) lo |= (uint32_t)bitv << oc;
            else         hi |= (uint32_t)bitv << (oc - 32);
        }
        int hidx = ((pi + 1) * 9 + pj + 1) * 2;
        if (lo) atomicOr(&s_H2[hidx], lo);
        if (hi) atomicOr(&s_H2[hidx + 1], hi);
    }
    __syncthreads();

    // ---- conv3 (64->16) + bias + relu -> h3T: 196 threads = 49 pos x 4 ----
    if (t < 196) {
        int pos = t >> 2, grp = t & 3;
        int pi, pj;
        if (pos < 25) { pi = 1 + pos / 5; pj = 1 + pos % 5; }
        else {
            int b = pos - 25;
            if (b < 7)       { pi = 0; pj = b; }
            else if (b < 14) { pi = 6; pj = b - 7; }
            else if (b < 19) { pi = b - 13; pj = 0; }
            else             { pi = b - 18; pj = 6; }
        }
        uint32_t cc[18];
#pragma unroll
        for (int kh = 0; kh < 3; ++kh)
#pragma unroll
            for (int kw = 0; kw < 3; ++kw) {
                int bidx = ((pi + kh) * 9 + pj + kw) * 2;
                cc[(kh * 3 + kw) * 2] = s_H2[bidx];
                cc[(kh * 3 + kw) * 2 + 1] = s_H2[bidx + 1];
            }
        const bool border = pos >= 25;
        int rowAny = (pi == 0) | (pi == 6);
        int colAny = (pj == 0) | (pj == 6);
        int rsh = (pi == 6) ? 8 : 0;
        int csh = (pj == 6) ? 24 : 16;
        int psh = (((pi == 6) ? 2 : 0) + ((pj == 6) ? 1 : 0)) * 8;
        int nInv = 3 * rowAny + 3 * colAny - (rowAny & colAny);
        int NvB = 64 * (9 - nInv);
#pragma unroll
        for (int o = 0; o < 4; ++o) {
            int oc = grp * 4 + o;
            const uint32_t* wp = &s_W3[oc * 18];
            int S = 0;
#pragma unroll
            for (int k = 0; k < 18; ++k) S += __popc(cc[k] ^ wp[k]);
            int corr = 0;
            if (border) {
                uint32_t cw0 = s_c3[oc * 2], cw1 = s_c3[oc * 2 + 1];
                corr = (rowAny ? (int)((cw0 >> rsh) & 0xFF) : 0) +
                       (colAny ? (int)((cw0 >> csh) & 0xFF) : 0) -
                       ((rowAny & colAny) ? (int)((cw1 >> psh) & 0xFF) : 0);
            }
            int v = NvB - 2 * (S - corr);
            float h = (float)v + s_b3[oc];
            h3T[(oc * 49 + pi * 7 + pj) * 4096 + img] = fmaxf(h, 0.f);
        }
    }
}

// ---------------- FC1: [4096x800] x [800x256] -> relu -> h1T (dbuf) ---------
__global__ __launch_bounds__(256, 1) void fc1_gemm(
    const float* __restrict__ aT, const float* __restrict__ bT,
    const float* __restrict__ bias, float* __restrict__ oT) {
    __shared__ float As[2][50 * 68];
    __shared__ float Bs[2][50 * 68];
    const int t = threadIdx.x;
    const int tx = t & 15, ty = t >> 4;
    const int img0 = blockIdx.x * 64;
    const int n0 = blockIdx.y * 64;
    float acc[4][4] = {{0.f}};

#pragma unroll
    for (int s = 0; s < 4; ++s) {
        int v = t + s * 256;
        if (v < 800) {
            int kk = v >> 4, i4 = (v & 15) * 4;
            *(float4*)&As[0][kk * 68 + i4] = *(const float4*)&aT[kk * 4096 + img0 + i4];
            *(float4*)&Bs[0][kk * 68 + i4] = *(const float4*)&bT[kk * 256 + n0 + i4];
        }
    }
    __syncthreads();
    int cur = 0;
    for (int ch = 0; ch < 16; ++ch) {
        float4 ra[4], rb[4];
        if (ch < 15) {
            int kc = (ch + 1) * 50;
#pragma unroll
            for (int s = 0; s < 4; ++s) {
                int v = t + s * 256;
                if (v < 800) {
                    int kk = v >> 4, i4 = (v & 15) * 4;
                    ra[s] = *(const float4*)&aT[(kc + kk) * 4096 + img0 + i4];
                    rb[s] = *(const float4*)&bT[(kc + kk) * 256 + n0 + i4];
                }
            }
        }
#pragma unroll 5
        for (int kk = 0; kk < 50; ++kk) {
            float4 a = *(const float4*)&As[cur][kk * 68 + ty * 4];
            float4 b = *(const float4*)&Bs[cur][kk * 68 + tx * 4];
            acc[0][0] += a.x * b.x; acc[0][1] += a.x * b.y;
            acc[0][2] += a.x * b.z; acc[0][3] += a.x * b.w;
            acc[1][0] += a.y * b.x; acc[1][1] += a.y * b.y;
            acc[1][2] += a.y * b.z; acc[1][3] += a.y * b.w;
            acc[2][0] += a.z * b.x; acc[2][1] += a.z * b.y;
            acc[2][2] += a.z * b.z; acc[2][3] += a.z * b.w;
            acc[3][0] += a.w * b.x; acc[3][1] += a.w * b.y;
            acc[3][2] += a.w * b.z; acc[3][3] += a.w * b.w;
        }
        if (ch < 15) {
#pragma unroll
            for (int s = 0; s < 4; ++s) {
                int v = t + s * 256;
                if (v < 800) {
                    int kk = v >> 4, i4 = (v & 15) * 4;
                    *(float4*)&As[cur ^ 1][kk * 68 + i4] = ra[s];
                    *(float4*)&Bs[cur ^ 1][kk * 68 + i4] = rb[s];
                }
            }
        }
        __syncthreads();
        cur ^= 1;
    }
    float4 bb = *(const float4*)&bias[n0 + tx * 4];
    float bv[4] = {bb.x, bb.y, bb.z, bb.w};
#pragma unroll
    for (int jj = 0; jj < 4; ++jj) {
        float4 ov;
        ov.x = acc[0][jj] + bv[jj]; ov.x = ov.x > 0.f ? ov.x : 0.f;
        ov.y = acc[1][jj] + bv[jj]; ov.y = ov.y > 0.f ? ov.y : 0.f;
        ov.z = acc[2][jj] + bv[jj]; ov.z = ov.z > 0.f ? ov.z : 0.f;
        ov.w = acc[3][jj] + bv[jj]; ov.w = ov.w > 0.f ? ov.w : 0.f;
        *(float4*)&oT[(n0 + tx * 4 + jj) * 4096 + img0 + ty * 4] = ov;
    }
}

// ---------------- FC2: [4096x256] x [256x128] -> relu -> h2T (dbuf) ---------
__global__ __launch_bounds__(256, 1) void fc2_gemm(
    const float* __restrict__ aT, const float* __restrict__ bT,
    const float* __restrict__ bias, float* __restrict__ oT) {
    __shared__ float As[2][64 * 68];
    __shared__ float Bs[2][64 * 36];
    const int t = threadIdx.x;
    const int tx = t & 15, ty = t >> 4;
    const int img0 = blockIdx.x * 64;
    const int n0 = blockIdx.y * 32;
    float acc[4][2] = {{0.f}};

#pragma unroll
    for (int s = 0; s < 4; ++s) {
        int v = t + s * 256;
        int kk = v >> 4, i4 = (v & 15) * 4;
        *(float4*)&As[0][kk * 68 + i4] = *(const float4*)&aT[kk * 4096 + img0 + i4];
    }
#pragma unroll
    for (int s = 0; s < 2; ++s) {
        int v = t + s * 256;
        int kk = v >> 3, n4 = (v & 7) * 4;
        *(float4*)&Bs[0][kk * 36 + n4] = *(const float4*)&bT[kk * 128 + n0 + n4];
    }
    __syncthreads();
    int cur = 0;
    for (int ch = 0; ch < 4; ++ch) {
        float4 ra[4]; float4 rb[2];
        if (ch < 3) {
            int kc = (ch + 1) * 64;
#pragma unroll
            for (int s = 0; s < 4; ++s) {
                int v = t + s * 256;
                int kk = v >> 4, i4 = (v & 15) * 4;
                ra[s] = *(const float4*)&aT[(kc + kk) * 4096 + img0 + i4];
            }
#pragma unroll
            for (int s = 0; s < 2; ++s) {
                int v = t + s * 256;
                int kk = v >> 3, n4 = (v & 7) * 4;
                rb[s] = *(const float4*)&bT[(kc + kk) * 128 + n0 + n4];
            }
        }
#pragma unroll 4
        for (int kk = 0; kk < 64; ++kk) {
            float4 a = *(const float4*)&As[cur][kk * 68 + ty * 4];
            float2 b = *(const float2*)&Bs[cur][kk * 36 + tx * 2];
            acc[0][0] += a.x * b.x; acc[0][1] += a.x * b.y;
            acc[1][0] += a.y * b.x; acc[1][1] += a.y * b.y;
            acc[2][0] += a.z * b.x; acc[2][1] += a.z * b.y;
            acc[3][0] += a.w * b.x; acc[3][1] += a.w * b.y;
        }
        if (ch < 3) {
#pragma unroll
            for (int s = 0; s < 4; ++s) {
                int v = t + s * 256;
                int kk = v >> 4, i4 = (v & 15) * 4;
                *(float4*)&As[cur ^ 1][kk * 68 + i4] = ra[s];
            }
#pragma unroll
            for (int s = 0; s < 2; ++s) {
                int v = t + s * 256;
                int kk = v >> 3, n4 = (v & 7) * 4;
                *(float4*)&Bs[cur ^ 1][kk * 36 + n4] = rb[s];
            }
        }
        __syncthreads();
        cur ^= 1;
    }
#pragma unroll
    for (int j = 0; j < 2; ++j) {
        int n = n0 + tx * 2 + j;
        float bj = bias[n];
        float4 ov;
        ov.x = acc[0][j] + bj; ov.x = ov.x > 0.f ? ov.x : 0.f;
        ov.y = acc[1][j] + bj; ov.y = ov.y > 0.f ? ov.y : 0.f;
        ov.z = acc[2][j] + bj; ov.z = ov.z > 0.f ? ov.z : 0.f;
        ov.w = acc[3][j] + bj; ov.w = ov.w > 0.f ? ov.w : 0.f;
        *(float4*)&oT[n * 4096 + img0 + ty * 4] = ov;
    }
}

// ---------------- FC3: [4096x128] x [128x10] -> out -------------------------
__global__ __launch_bounds__(256) void fc3_gemm(
    const float* __restrict__ aT, const float* __restrict__ w,
    const float* __restrict__ bias, float* __restrict__ out) {
    int id = blockIdx.x * 256 + threadIdx.x;   // 40960
    int n = id >> 12, img = id & 4095;
    const float* wr = w + n * 128;
    float a0 = 0.f, a1 = 0.f, a2 = 0.f, a3 = 0.f;
#pragma unroll 8
    for (int k = 0; k < 128; k += 4) {
        a0 += aT[(k + 0) * 4096 + img] * wr[k + 0];
        a1 += aT[(k + 1) * 4096 + img] * wr[k + 1];
        a2 += aT[(k + 2) * 4096 + img] * wr[k + 2];
        a3 += aT[(k + 3) * 4096 + img] * wr[k + 3];
    }
    out[img * 10 + n] = (a0 + a1) + (a2 + a3) + bias[n];
}

extern "C" void kernel_launch(void* const* d_in, const int* in_sizes, int n_in,
                              void* d_out, int out_size, void* d_ws, size_t ws_size,
                              hipStream_t stream) {
    const float* x     = (const float*)d_in[0];
    const float* w1    = (const float*)d_in[1];
    const float* b1    = (const float*)d_in[2];
    const float* w2    = (const float*)d_in[3];
    const float* b2    = (const float*)d_in[4];
    const float* w3    = (const float*)d_in[5];
    const float* b3    = (const float*)d_in[6];
    const float* fc1_w = (const float*)d_in[7];
    const float* fc1_b = (const float*)d_in[8];
    const float* fc2_w = (const float*)d_in[9];
    const float* fc2_b = (const float*)d_in[10];
    const float* fc3_w = (const float*)d_in[11];
    const float* fc3_b = (const float*)d_in[12];
    float* out = (float*)d_out;

    const int B = in_sizes[0] / 784;  // 4096
    char* ws = (char*)d_ws;
    uint32_t* pw = (uint32_t*)(ws + OFF_PW);
    float* w1T = (float*)(ws + OFF_W1T);
    float* w2T = (float*)(ws + OFF_W2T);
    float* h3T = (float*)(ws + OFF_H3T);
    float* h1T = (float*)(ws + OFF_H1T);
    float* h2T = (float*)(ws + OFF_H2T);

    hipMemsetAsync(pw, 0, 896 * 4, stream);
    hipLaunchKernelGGL(prep, dim3(1294), dim3(256), 0, stream,
                       w1, w2, w3, fc1_w, fc2_w, pw, w1T, w2T, h3T);
    hipLaunchKernelGGL(conv_stack, dim3(B), dim3(256), 0, stream,
                       x, b1, b2, b3, pw, h3T);
    hipLaunchKernelGGL(fc1_gemm, dim3(B / 64, 4), dim3(256), 0, stream,
                       h3T, w1T, fc1_b, h1T);
    hipLaunchKernelGGL(fc2_gemm, dim3(B / 64, 4), dim3(256), 0, stream,
                       h1T, w2T, fc2_b, h2T);
    hipLaunchKernelGGL(fc3_gemm, dim3(B * 10 / 256), dim3(256), 0, stream,
                       h2T, fc3_w, fc3_b, out);
}

// Round 4
// 224.883 us; speedup vs baseline: 1.1139x; 1.1139x over previous
//
#include <hip/hip_runtime.h>
#include <cstdint>

// ---------------- ws layout (bytes) ----------------
#define OFF_PW    0
#define OFF_W1T   4096
#define OFF_W2T   823296
#define OFF_H3T   954368
#define OFF_H1T   14061568
#define OFF_H2T   18255872

// ---------------- prep: transpose FC weights + pack conv sign bits ----------
// One thread per output element / packed word. No atomics, fully rewritten
// every call (ws is re-poisoned).
__global__ __launch_bounds__(256) void prep(
    const float* __restrict__ w1, const float* __restrict__ w2,
    const float* __restrict__ w3,
    const float* __restrict__ fc1_w, const float* __restrict__ fc2_w,
    uint32_t* __restrict__ pw, float* __restrict__ w1T,
    float* __restrict__ w2T, float* __restrict__ h3T) {
    int idx = blockIdx.x * 256 + threadIdx.x;
    if (idx < 204800) {               // fc1_wT [800][256]
        int k = idx >> 8, n = idx & 255;
        w1T[idx] = (k < 784) ? fc1_w[n * 784 + k] : 0.f;
        return;
    }
    idx -= 204800;
    if (idx < 32768) {                // fc2_wT [256][128]
        int k = idx >> 7, n = idx & 127;
        w2T[idx] = fc2_w[n * 256 + k];
        return;
    }
    idx -= 32768;
    if (idx < 65536) {                // zero h3T pad rows 784..799
        h3T[784 * 4096 + idx] = 0.f;
        return;
    }
    idx -= 65536;
    if (idx >= 896) return;
    if (idx < 32) {                   // pw[c]: bit tap = sign(w1[c][tap])
        uint32_t b = 0;
#pragma unroll
        for (int k = 0; k < 9; ++k) b |= (w1[idx * 9 + k] > 0.f ? 1u : 0u) << k;
        pw[idx] = b;
    } else if (idx < 608) {           // pw[32+oc*9+tap]: bit ic
        int e = idx - 32;
        int oc = e / 9, tap = e - oc * 9;
        uint32_t b = 0;
#pragma unroll
        for (int ic = 0; ic < 32; ++ic)
            b |= (w2[(oc * 32 + ic) * 9 + tap] > 0.f ? 1u : 0u) << ic;
        pw[idx] = b;
    } else {                          // pw[608+oc*18+tap*2+half]: bit ic
        int e = idx - 608;
        int oc = e / 18, r = e - oc * 18;
        int tap = r >> 1, half = r & 1;
        uint32_t b = 0;
#pragma unroll
        for (int ic = 0; ic < 32; ++ic)
            b |= (w3[(oc * 64 + half * 32 + ic) * 9 + tap] > 0.f ? 1u : 0u) << ic;
        pw[idx] = b;
    }
}

__device__ __forceinline__ uint32_t bfe3(uint32_t r, int j) { return (r >> j) & 7u; }

// ---------------- conv stack: 8 images per block ---------------------------
// conv1: thread-per-(img,pooledpos), 32-ch loop.
// conv2: wave-per-(img,pooledpos), lane = oc (64), weights in VGPRs, __ballot.
// conv3: wave-per-(imgquad,pos), lane = (oc16, img4), weights in VGPRs.
__global__ __launch_bounds__(256, 2) void conv_stack(
    const float* __restrict__ x, const float* __restrict__ b1,
    const float* __restrict__ b2, const float* __restrict__ b3,
    const uint32_t* __restrict__ pw, float* __restrict__ h3T) {
    __shared__ uint32_t s_xr[8 * 36];    // pre-shifted (<<1) row bits, stride 36
    __shared__ uint32_t s_H1[8 * 260];   // padded 16x16 planes, stride 260
    __shared__ uint32_t s_H2[8 * 164];   // padded 9x9 x2 planes, stride 164
    __shared__ uint32_t s_w1[32];
    __shared__ int s_sth1[32], s_ic1[32], s_ic2[64];
    __shared__ uint32_t s_W2t[576];      // [tap][oc]
    __shared__ uint32_t s_W3t[288];      // [word18][oc16]
    __shared__ float s_b3[16];

    const int t = threadIdx.x;
    const int lane = t & 63;
    const int wid = t >> 6;
    const int img0 = blockIdx.x * 8;

    // ---- setup (amortized over 8 images) ----
    for (int i = t; i < 8 * 260; i += 256) s_H1[i] = 0;
    for (int i = t; i < 8 * 164; i += 256) s_H2[i] = 0;
    if (t < 224) {
        int im = t / 28, row = t - im * 28;
        const float4* xr = (const float4*)(x + (img0 + im) * 784 + row * 28);
        uint32_t b = 0;
#pragma unroll
        for (int q = 0; q < 7; ++q) {
            float4 v = xr[q];
            b |= (v.x > 0.f ? 1u : 0u) << (q * 4 + 0);
            b |= (v.y > 0.f ? 1u : 0u) << (q * 4 + 1);
            b |= (v.z > 0.f ? 1u : 0u) << (q * 4 + 2);
            b |= (v.w > 0.f ? 1u : 0u) << (q * 4 + 3);
        }
        s_xr[im * 36 + row] = b << 1;    // bit (c+1) = col c; bits 0,29..31 = pad
    }
    if (t < 32) {
        s_w1[t] = pw[t];
        int ic = (int)floorf(-b1[t]) + 1;
        s_ic1[t] = ic;
        s_sth1[t] = (9 - ic) >> 1;
    } else if (t >= 32 && t < 96) {
        s_ic2[t - 32] = (int)floorf(-b2[t - 32]) + 1;
    } else if (t >= 96 && t < 112) {
        s_b3[t - 96] = b3[t - 96];
    }
    for (int i = t; i < 576; i += 256)
        s_W2t[i] = pw[32 + (i & 63) * 9 + (i >> 6)];
    for (int i = t; i < 288; i += 256)
        s_W3t[i] = pw[608 + (i & 15) * 18 + (i >> 4)];
    __syncthreads();

    // ---- conv1: 1568 tasks (pos-major, img fastest), interior 0..1151 ----
    for (int task = t; task < 1568; task += 256) {
        int pid = task >> 3, im = task & 7;
        int pi, pj;
        if (pid < 144) { pi = 1 + pid / 12; pj = 1 + pid - (pid / 12) * 12; }
        else {
            int b = pid - 144;
            if (b < 14)      { pi = 0;  pj = b; }
            else if (b < 28) { pi = 13; pj = b - 14; }
            else if (b < 40) { pi = 1 + (b - 28); pj = 0; }
            else             { pi = 1 + (b - 40); pj = 13; }
        }
        const uint32_t* xr = &s_xr[im * 36];
        int y0 = 2 * pi - 1;
        uint32_t r0 = (pi > 0)  ? xr[y0]     : 0u;
        uint32_t r1 = xr[y0 + 1];
        uint32_t r2 = xr[y0 + 2];
        uint32_t r3 = (pi < 13) ? xr[y0 + 3] : 0u;
        int j0 = 2 * pj, j1 = 2 * pj + 1;
        uint32_t s00 = bfe3(r0, j0) | (bfe3(r1, j0) << 3) | (bfe3(r2, j0) << 6);
        uint32_t s01 = bfe3(r0, j1) | (bfe3(r1, j1) << 3) | (bfe3(r2, j1) << 6);
        uint32_t s10 = bfe3(r1, j0) | (bfe3(r2, j0) << 3) | (bfe3(r3, j0) << 6);
        uint32_t s11 = bfe3(r1, j1) | (bfe3(r2, j1) << 3) | (bfe3(r3, j1) << 6);
        uint32_t word = 0;
        if (pid < 144) {
#pragma unroll
            for (int c = 0; c < 32; ++c) {
                uint32_t w = s_w1[c];
                int S = min(min(__popc(s00 ^ w), __popc(s01 ^ w)),
                            min(__popc(s10 ^ w), __popc(s11 ^ w)));
                word |= (uint32_t)(S <= s_sth1[c]) << c;
            }
        } else {
            uint32_t iT = (pi == 0)  ? 0x7u   : 0u;
            uint32_t iB = (pi == 13) ? 0x1C0u : 0u;
            uint32_t iL = (pj == 0)  ? 0x49u  : 0u;
            uint32_t iR = (pj == 13) ? 0x124u : 0u;
            uint32_t i00 = iT | iL, i01 = iT | iR, i10 = iB | iL, i11 = iB | iR;
            int n00 = 9 - __popc(i00), n01 = 9 - __popc(i01);
            int n10 = 9 - __popc(i10), n11 = 9 - __popc(i11);
#pragma unroll
            for (int c = 0; c < 32; ++c) {
                uint32_t w = s_w1[c];
                int v0 = n00 - 2 * (__popc(s00 ^ w) - __popc(w & i00));
                int v1 = n01 - 2 * (__popc(s01 ^ w) - __popc(w & i01));
                int v2 = n10 - 2 * (__popc(s10 ^ w) - __popc(w & i10));
                int v3 = n11 - 2 * (__popc(s11 ^ w) - __popc(w & i11));
                int vm = max(max(v0, v1), max(v2, v3));
                word |= (uint32_t)(vm >= s_ic1[c]) << c;
            }
        }
        s_H1[im * 260 + (pi + 1) * 16 + (pj + 1)] = word;
    }
    __syncthreads();

    // ---- conv2: 392 wave-tasks; lane = oc; weights persistent in VGPRs ----
    {
        uint32_t w0 = s_W2t[0 * 64 + lane], w1r = s_W2t[1 * 64 + lane],
                 w2r = s_W2t[2 * 64 + lane], w3r = s_W2t[3 * 64 + lane],
                 w4 = s_W2t[4 * 64 + lane], w5 = s_W2t[5 * 64 + lane],
                 w6 = s_W2t[6 * 64 + lane], w7 = s_W2t[7 * 64 + lane],
                 w8 = s_W2t[8 * 64 + lane];
        int ic2 = s_ic2[lane];
        int sth2 = (288 - ic2) >> 1;
        int pc0 = __popc(w0), pc1 = __popc(w1r), pc2 = __popc(w2r);
        int pc3 = __popc(w3r), pc5 = __popc(w5), pc6 = __popc(w6);
        int pc7 = __popc(w7), pc8 = __popc(w8);
        int topc = pc0 + pc1 + pc2, botc = pc6 + pc7 + pc8;
        int lefc = pc0 + pc3 + pc6, rigc = pc2 + pc5 + pc8;

        for (int wt = wid; wt < 392; wt += 4) {
            int im = wt & 7, pos = wt >> 3;
            int pi, pj;
            if (pos < 25) { pi = 1 + pos / 5; pj = 1 + pos - (pos / 5) * 5; }
            else {
                int b = pos - 25;
                if (b < 7)       { pi = 0; pj = b; }
                else if (b < 14) { pi = 6; pj = b - 7; }
                else if (b < 19) { pi = b - 13; pj = 0; }
                else             { pi = b - 18; pj = 6; }
            }
            int base = im * 260 + 2 * pi * 16 + 2 * pj;
            uint2 ra0 = *(const uint2*)&s_H1[base],      ra1 = *(const uint2*)&s_H1[base + 2];
            uint2 rb0 = *(const uint2*)&s_H1[base + 16], rb1 = *(const uint2*)&s_H1[base + 18];
            uint2 rc0 = *(const uint2*)&s_H1[base + 32], rc1 = *(const uint2*)&s_H1[base + 34];
            uint2 rd0 = *(const uint2*)&s_H1[base + 48], rd1 = *(const uint2*)&s_H1[base + 50];
            uint32_t c00 = ra0.x, c01 = ra0.y, c02 = ra1.x, c03 = ra1.y;
            uint32_t c10 = rb0.x, c11 = rb0.y, c12 = rb1.x, c13 = rb1.y;
            uint32_t c20 = rc0.x, c21 = rc0.y, c22 = rc1.x, c23 = rc1.y;
            uint32_t c30 = rd0.x, c31 = rd0.y, c32 = rd1.x, c33 = rd1.y;
            int S00 = __popc(c00 ^ w0) + __popc(c01 ^ w1r) + __popc(c02 ^ w2r)
                    + __popc(c10 ^ w3r) + __popc(c11 ^ w4) + __popc(c12 ^ w5)
                    + __popc(c20 ^ w6) + __popc(c21 ^ w7) + __popc(c22 ^ w8);
            int S01 = __popc(c01 ^ w0) + __popc(c02 ^ w1r) + __popc(c03 ^ w2r)
                    + __popc(c11 ^ w3r) + __popc(c12 ^ w4) + __popc(c13 ^ w5)
                    + __popc(c21 ^ w6) + __popc(c22 ^ w7) + __popc(c23 ^ w8);
            int S10 = __popc(c10 ^ w0) + __popc(c11 ^ w1r) + __popc(c12 ^ w2r)
                    + __popc(c20 ^ w3r) + __popc(c21 ^ w4) + __popc(c22 ^ w5)
                    + __popc(c30 ^ w6) + __popc(c31 ^ w7) + __popc(c32 ^ w8);
            int S11 = __popc(c11 ^ w0) + __popc(c12 ^ w1r) + __popc(c13 ^ w2r)
                    + __popc(c21 ^ w3r) + __popc(c22 ^ w4) + __popc(c23 ^ w5)
                    + __popc(c31 ^ w6) + __popc(c32 ^ w7) + __popc(c33 ^ w8);
            int pred;
            if (pos < 25) {
                int Sm = min(min(S00, S01), min(S10, S11));
                pred = (Sm <= sth2);
            } else {
                int vmax;
                {   // p(0,0): top iff pi==0, left iff pj==0
                    int rI = (pi == 0), cI = (pj == 0);
                    int corr = (rI ? topc : 0) + (cI ? lefc : 0) - ((rI & cI) ? pc0 : 0);
                    int nv = 32 * (9 - 3 * rI - 3 * cI + (rI & cI));
                    vmax = nv - 2 * (S00 - corr);
                }
                {   // p(0,1): top iff pi==0, right iff pj==6
                    int rI = (pi == 0), cI = (pj == 6);
                    int corr = (rI ? topc : 0) + (cI ? rigc : 0) - ((rI & cI) ? pc2 : 0);
                    int nv = 32 * (9 - 3 * rI - 3 * cI + (rI & cI));
                    vmax = max(vmax, nv - 2 * (S01 - corr));
                }
                {   // p(1,0): bottom iff pi==6, left iff pj==0
                    int rI = (pi == 6), cI = (pj == 0);
                    int corr = (rI ? botc : 0) + (cI ? lefc : 0) - ((rI & cI) ? pc6 : 0);
                    int nv = 32 * (9 - 3 * rI - 3 * cI + (rI & cI));
                    vmax = max(vmax, nv - 2 * (S10 - corr));
                }
                {   // p(1,1): bottom iff pi==6, right iff pj==6
                    int rI = (pi == 6), cI = (pj == 6);
                    int corr = (rI ? botc : 0) + (cI ? rigc : 0) - ((rI & cI) ? pc8 : 0);
                    int nv = 32 * (9 - 3 * rI - 3 * cI + (rI & cI));
                    vmax = max(vmax, nv - 2 * (S11 - corr));
                }
                pred = (vmax >= ic2);
            }
            unsigned long long m = __ballot(pred);
            if (lane == 0) {
                *(uint2*)&s_H2[im * 164 + ((pi + 1) * 9 + (pj + 1)) * 2] =
                    make_uint2((uint32_t)m, (uint32_t)(m >> 32));
            }
        }
    }
    __syncthreads();

    // ---- conv3: 98 wave-tasks; lane = (oc 0..15, imgsub 0..3) ----
    {
        int oc = lane & 15, iq = lane >> 4;
        uint32_t w[18];
#pragma unroll
        for (int k = 0; k < 18; ++k) w[k] = s_W3t[k * 16 + oc];
        float bias3 = s_b3[oc];
        int pc[9];
#pragma unroll
        for (int k = 0; k < 9; ++k) pc[k] = __popc(w[2 * k]) + __popc(w[2 * k + 1]);
        int topc = pc[0] + pc[1] + pc[2], botc = pc[6] + pc[7] + pc[8];
        int lefc = pc[0] + pc[3] + pc[6], rigc = pc[2] + pc[5] + pc[8];

        for (int wt = wid; wt < 98; wt += 4) {
            int iq2 = wt & 1, pos = wt >> 1;
            int im = iq2 * 4 + iq;
            int pi, pj;
            if (pos < 25) { pi = 1 + pos / 5; pj = 1 + pos - (pos / 5) * 5; }
            else {
                int b = pos - 25;
                if (b < 7)       { pi = 0; pj = b; }
                else if (b < 14) { pi = 6; pj = b - 7; }
                else if (b < 19) { pi = b - 13; pj = 0; }
                else             { pi = b - 18; pj = 6; }
            }
            const uint32_t* hp = &s_H2[im * 164];
            int S = 0;
#pragma unroll
            for (int kh = 0; kh < 3; ++kh)
#pragma unroll
                for (int kw = 0; kw < 3; ++kw) {
                    uint2 cc = *(const uint2*)&hp[((pi + kh) * 9 + (pj + kw)) * 2];
                    int k = kh * 3 + kw;
                    S += __popc(cc.x ^ w[2 * k]) + __popc(cc.y ^ w[2 * k + 1]);
                }
            int v;
            if (pos < 25) {
                v = 576 - 2 * S;
            } else {
                int rT = (pi == 0), rB = (pi == 6), cL = (pj == 0), cR = (pj == 6);
                int rA = rT | rB, cA = cL | cR;
                int corr = (rT ? topc : 0) + (rB ? botc : 0) +
                           (cL ? lefc : 0) + (cR ? rigc : 0);
                if (rT & cL) corr -= pc[0];
                if (rT & cR) corr -= pc[2];
                if (rB & cL) corr -= pc[6];
                if (rB & cR) corr -= pc[8];
                int nInv = 3 * rA + 3 * cA - (rA & cA);
                v = 64 * (9 - nInv) - 2 * (S - corr);
            }
            float h = fmaxf((float)v + bias3, 0.f);
            h3T[(oc * 49 + pi * 7 + pj) * 4096 + img0 + im] = h;
        }
    }
}

// ---------------- FC1: [4096x800]x[800x256] -> relu -> h1T ------------------
// tile 64 img x 32 n, KC=160, grid (64,8)=512 blocks = 2/CU.
__global__ __launch_bounds__(256, 2) void fc1_gemm(
    const float* __restrict__ aT, const float* __restrict__ bT,
    const float* __restrict__ bias, float* __restrict__ oT) {
    const int LDA = 68, LDB = 36;
    __shared__ float As[160 * LDA];
    __shared__ float Bs[160 * LDB];
    const int t = threadIdx.x;
    const int tx = t & 15, ty = t >> 4;
    const int img0 = blockIdx.x * 64;
    const int n0 = blockIdx.y * 32;
    float acc[4][2] = {{0.f}};

    for (int kc = 0; kc < 800; kc += 160) {
#pragma unroll
        for (int s = 0; s < 10; ++s) {
            int v = t + s * 256;
            int kk = v >> 4, q = (v & 15) * 4;
            *(float4*)&As[kk * LDA + q] =
                *(const float4*)&aT[(kc + kk) * 4096 + img0 + q];
        }
#pragma unroll
        for (int s = 0; s < 5; ++s) {
            int v = t + s * 256;
            int kk = v >> 3, q = (v & 7) * 4;
            *(float4*)&Bs[kk * LDB + q] =
                *(const float4*)&bT[(kc + kk) * 256 + n0 + q];
        }
        __syncthreads();
#pragma unroll 8
        for (int kk = 0; kk < 160; ++kk) {
            float4 a = *(const float4*)&As[kk * LDA + ty * 4];
            float2 b = *(const float2*)&Bs[kk * LDB + tx * 2];
            acc[0][0] += a.x * b.x; acc[0][1] += a.x * b.y;
            acc[1][0] += a.y * b.x; acc[1][1] += a.y * b.y;
            acc[2][0] += a.z * b.x; acc[2][1] += a.z * b.y;
            acc[3][0] += a.w * b.x; acc[3][1] += a.w * b.y;
        }
        __syncthreads();
    }
#pragma unroll
    for (int j = 0; j < 2; ++j) {
        int n = n0 + tx * 2 + j;
        float bj = bias[n];
        float4 ov;
        ov.x = fmaxf(acc[0][j] + bj, 0.f);
        ov.y = fmaxf(acc[1][j] + bj, 0.f);
        ov.z = fmaxf(acc[2][j] + bj, 0.f);
        ov.w = fmaxf(acc[3][j] + bj, 0.f);
        *(float4*)&oT[n * 4096 + img0 + ty * 4] = ov;
    }
}

// ---------------- FC2: [4096x256]x[256x128] -> relu -> h2T ------------------
// tile 32 img x 32 n, single K-chunk (256), grid (128,4)=512 = 2/CU.
__global__ __launch_bounds__(256, 2) void fc2_gemm(
    const float* __restrict__ aT, const float* __restrict__ bT,
    const float* __restrict__ bias, float* __restrict__ oT) {
    const int LD = 36;
    __shared__ float As[256 * LD];
    __shared__ float Bs[256 * LD];
    const int t = threadIdx.x;
    const int tx = t & 15, ty = t >> 4;
    const int img0 = blockIdx.x * 32;
    const int n0 = blockIdx.y * 32;
    float acc[2][2] = {{0.f}};

#pragma unroll
    for (int s = 0; s < 8; ++s) {
        int v = t + s * 256;
        int kk = v >> 3, q = (v & 7) * 4;
        *(float4*)&As[kk * LD + q] = *(const float4*)&aT[kk * 4096 + img0 + q];
        *(float4*)&Bs[kk * LD + q] = *(const float4*)&bT[kk * 128 + n0 + q];
    }
    __syncthreads();
#pragma unroll 8
    for (int kk = 0; kk < 256; ++kk) {
        float2 a = *(const float2*)&As[kk * LD + ty * 2];
        float2 b = *(const float2*)&Bs[kk * LD + tx * 2];
        acc[0][0] += a.x * b.x; acc[0][1] += a.x * b.y;
        acc[1][0] += a.y * b.x; acc[1][1] += a.y * b.y;
    }
#pragma unroll
    for (int j = 0; j < 2; ++j) {
        int n = n0 + tx * 2 + j;
        float bj = bias[n];
        float2 ov;
        ov.x = fmaxf(acc[0][j] + bj, 0.f);
        ov.y = fmaxf(acc[1][j] + bj, 0.f);
        *(float2*)&oT[n * 4096 + img0 + ty * 2] = ov;
    }
}

// ---------------- FC3: [4096x128]x[128x10] -> out ---------------------------
__global__ __launch_bounds__(256) void fc3_gemm(
    const float* __restrict__ aT, const float* __restrict__ w,
    const float* __restrict__ bias, float* __restrict__ out) {
    int id = blockIdx.x * 256 + threadIdx.x;   // 40960
    int n = id >> 12, img = id & 4095;
    const float* wr = w + n * 128;
    float a0 = 0.f, a1 = 0.f, a2 = 0.f, a3 = 0.f;
#pragma unroll 8
    for (int k = 0; k < 128; k += 4) {
        a0 += aT[(k + 0) * 4096 + img] * wr[k + 0];
        a1 += aT[(k + 1) * 4096 + img] * wr[k + 1];
        a2 += aT[(k + 2) * 4096 + img] * wr[k + 2];
        a3 += aT[(k + 3) * 4096 + img] * wr[k + 3];
    }
    out[img * 10 + n] = (a0 + a1) + (a2 + a3) + bias[n];
}

extern "C" void kernel_launch(void* const* d_in, const int* in_sizes, int n_in,
                              void* d_out, int out_size, void* d_ws, size_t ws_size,
                              hipStream_t stream) {
    const float* x     = (const float*)d_in[0];
    const float* w1    = (const float*)d_in[1];
    const float* b1    = (const float*)d_in[2];
    const float* w2    = (const float*)d_in[3];
    const float* b2    = (const float*)d_in[4];
    const float* w3    = (const float*)d_in[5];
    const float* b3    = (const float*)d_in[6];
    const float* fc1_w = (const float*)d_in[7];
    const float* fc1_b = (const float*)d_in[8];
    const float* fc2_w = (const float*)d_in[9];
    const float* fc2_b = (const float*)d_in[10];
    const float* fc3_w = (const float*)d_in[11];
    const float* fc3_b = (const float*)d_in[12];
    float* out = (float*)d_out;

    const int B = in_sizes[0] / 784;  // 4096
    char* ws = (char*)d_ws;
    uint32_t* pw = (uint32_t*)(ws + OFF_PW);
    float* w1T = (float*)(ws + OFF_W1T);
    float* w2T = (float*)(ws + OFF_W2T);
    float* h3T = (float*)(ws + OFF_H3T);
    float* h1T = (float*)(ws + OFF_H1T);
    float* h2T = (float*)(ws + OFF_H2T);

    hipLaunchKernelGGL(prep, dim3(1188), dim3(256), 0, stream,
                       w1, w2, w3, fc1_w, fc2_w, pw, w1T, w2T, h3T);
    hipLaunchKernelGGL(conv_stack, dim3(B / 8), dim3(256), 0, stream,
                       x, b1, b2, b3, pw, h3T);
    hipLaunchKernelGGL(fc1_gemm, dim3(B / 64, 8), dim3(256), 0, stream,
                       h3T, w1T, fc1_b, h1T);
    hipLaunchKernelGGL(fc2_gemm, dim3(B / 32, 4), dim3(256), 0, stream,
                       h1T, w2T, fc2_b, h2T);
    hipLaunchKernelGGL(fc3_gemm, dim3(B * 10 / 256), dim3(256), 0, stream,
                       h2T, fc3_w, fc3_b, out);
}

// Round 6
// 224.367 us; speedup vs baseline: 1.1164x; 1.0023x over previous
//
#include <hip/hip_runtime.h>
#include <cstdint>

// ---------------- ws layout (bytes) ----------------
#define OFF_PW    0
#define OFF_W1T   4096
#define OFF_W2T   823296
#define OFF_H3T   954368
#define OFF_H1T   14061568
#define OFF_H2T   18255872
// optional extension (used only if ws_size >= WS_NEED_EXT)
#define OFF_H1EXT 20353024ull            // 3 x 4 MB fc1 partials z=1..3
#define OFF_H2EXT 32935936ull            // 1 x 2 MB fc2 partial  z=1
#define WS_NEED_EXT 35033088ull

// ---------------- prep: transpose FC weights + pack conv sign bits ----------
__global__ __launch_bounds__(256) void prep(
    const float* __restrict__ w1, const float* __restrict__ w2,
    const float* __restrict__ w3,
    const float* __restrict__ fc1_w, const float* __restrict__ fc2_w,
    uint32_t* __restrict__ pw, float* __restrict__ w1T,
    float* __restrict__ w2T, float* __restrict__ h3T) {
    int idx = blockIdx.x * 256 + threadIdx.x;
    if (idx < 204800) {               // fc1_wT [800][256]
        int k = idx >> 8, n = idx & 255;
        w1T[idx] = (k < 784) ? fc1_w[n * 784 + k] : 0.f;
        return;
    }
    idx -= 204800;
    if (idx < 32768) {                // fc2_wT [256][128]
        int k = idx >> 7, n = idx & 127;
        w2T[idx] = fc2_w[n * 256 + k];
        return;
    }
    idx -= 32768;
    if (idx < 65536) {                // zero h3T pad rows 784..799
        h3T[784 * 4096 + idx] = 0.f;
        return;
    }
    idx -= 65536;
    if (idx >= 896) return;
    if (idx < 32) {
        uint32_t b = 0;
#pragma unroll
        for (int k = 0; k < 9; ++k) b |= (w1[idx * 9 + k] > 0.f ? 1u : 0u) << k;
        pw[idx] = b;
    } else if (idx < 608) {
        int e = idx - 32;
        int oc = e / 9, tap = e - oc * 9;
        uint32_t b = 0;
#pragma unroll
        for (int ic = 0; ic < 32; ++ic)
            b |= (w2[(oc * 32 + ic) * 9 + tap] > 0.f ? 1u : 0u) << ic;
        pw[idx] = b;
    } else {
        int e = idx - 608;
        int oc = e / 18, r = e - oc * 18;
        int tap = r >> 1, half = r & 1;
        uint32_t b = 0;
#pragma unroll
        for (int ic = 0; ic < 32; ++ic)
            b |= (w3[(oc * 64 + half * 32 + ic) * 9 + tap] > 0.f ? 1u : 0u) << ic;
        pw[idx] = b;
    }
}

__device__ __forceinline__ uint32_t bfe3(uint32_t r, int j) { return (r >> j) & 7u; }

// ---------------- conv stack: 4 images per block ---------------------------
__global__ __launch_bounds__(256, 4) void conv_stack(
    const float* __restrict__ x, const float* __restrict__ b1,
    const float* __restrict__ b2, const float* __restrict__ b3,
    const uint32_t* __restrict__ pw, float* __restrict__ h3T) {
    __shared__ __align__(16) uint32_t s_H1[4][16][16];
    __shared__ __align__(16) uint32_t s_H2[4][9][9][2];
    __shared__ uint32_t s_xr[4][32];
    __shared__ uint32_t s_w1[32];
    __shared__ int s_sth1[32], s_ic1[32], s_ic2[64];
    __shared__ uint32_t s_W2t[9][64];
    __shared__ uint32_t s_W3t[18][16];
    __shared__ float s_b3[16];

    const int t = threadIdx.x;
    const int lane = t & 63;
    const int wid = t >> 6;
    const int img0 = blockIdx.x * 4;

    // ---- setup ----
    {
        uint32_t* h1f = &s_H1[0][0][0];
        for (int i = t; i < 1024; i += 256) h1f[i] = 0;
        uint32_t* h2f = &s_H2[0][0][0][0];
        for (int i = t; i < 648; i += 256) h2f[i] = 0;
    }
    if (t < 32) {
        s_w1[t] = pw[t];
        int ic = (int)floorf(-b1[t]) + 1;
        s_ic1[t] = ic;
        s_sth1[t] = (9 - ic) >> 1;
    } else if (t < 96) {
        s_ic2[t - 32] = (int)floorf(-b2[t - 32]) + 1;
    } else if (t < 112) {
        s_b3[t - 96] = b3[t - 96];
    } else if (t >= 128 && t < 240) {
        int r = t - 128;
        int im = r / 28, row = r - im * 28;
        const float4* xr = (const float4*)(x + (img0 + im) * 784 + row * 28);
        uint32_t b = 0;
#pragma unroll
        for (int q = 0; q < 7; ++q) {
            float4 v = xr[q];
            b |= (v.x > 0.f ? 1u : 0u) << (q * 4 + 0);
            b |= (v.y > 0.f ? 1u : 0u) << (q * 4 + 1);
            b |= (v.z > 0.f ? 1u : 0u) << (q * 4 + 2);
            b |= (v.w > 0.f ? 1u : 0u) << (q * 4 + 3);
        }
        s_xr[im][row] = b << 1;
    }
    for (int i = t; i < 576; i += 256)
        s_W2t[i >> 6][i & 63] = pw[32 + (i & 63) * 9 + (i >> 6)];
    for (int i = t; i < 288; i += 256)
        s_W3t[i >> 4][i & 15] = pw[608 + (i & 15) * 18 + (i >> 4)];
    __syncthreads();

    // ---- conv1: 784 tasks = 196 pos x 4 img ----
    for (int task = t; task < 784; task += 256) {
        int im = task & 3, pid = task >> 2;
        int pi, pj;
        if (pid < 144) { pi = 1 + pid / 12; pj = 1 + pid - (pid / 12) * 12; }
        else {
            int b = pid - 144;
            if (b < 14)      { pi = 0;  pj = b; }
            else if (b < 28) { pi = 13; pj = b - 14; }
            else if (b < 40) { pi = 1 + (b - 28); pj = 0; }
            else             { pi = 1 + (b - 40); pj = 13; }
        }
        const uint32_t* xr = &s_xr[im][0];
        int y0 = 2 * pi - 1;
        uint32_t r0 = (pi > 0)  ? xr[y0]     : 0u;
        uint32_t r1 = xr[y0 + 1];
        uint32_t r2 = xr[y0 + 2];
        uint32_t r3 = (pi < 13) ? xr[y0 + 3] : 0u;
        int j0 = 2 * pj, j1 = 2 * pj + 1;
        uint32_t s00 = bfe3(r0, j0) | (bfe3(r1, j0) << 3) | (bfe3(r2, j0) << 6);
        uint32_t s01 = bfe3(r0, j1) | (bfe3(r1, j1) << 3) | (bfe3(r2, j1) << 6);
        uint32_t s10 = bfe3(r1, j0) | (bfe3(r2, j0) << 3) | (bfe3(r3, j0) << 6);
        uint32_t s11 = bfe3(r1, j1) | (bfe3(r2, j1) << 3) | (bfe3(r3, j1) << 6);
        uint32_t word = 0;
        if (pid < 144) {
#pragma unroll 4
            for (int c = 0; c < 32; ++c) {
                uint32_t w = s_w1[c];
                int S = min(min(__popc(s00 ^ w), __popc(s01 ^ w)),
                            min(__popc(s10 ^ w), __popc(s11 ^ w)));
                word |= (uint32_t)(S <= s_sth1[c]) << c;
            }
        } else {
            uint32_t iT = (pi == 0)  ? 0x7u   : 0u;
            uint32_t iB = (pi == 13) ? 0x1C0u : 0u;
            uint32_t iL = (pj == 0)  ? 0x49u  : 0u;
            uint32_t iR = (pj == 13) ? 0x124u : 0u;
            uint32_t i00 = iT | iL, i01 = iT | iR, i10 = iB | iL, i11 = iB | iR;
            int n00 = 9 - __popc(i00), n01 = 9 - __popc(i01);
            int n10 = 9 - __popc(i10), n11 = 9 - __popc(i11);
#pragma unroll 4
            for (int c = 0; c < 32; ++c) {
                uint32_t w = s_w1[c];
                int v0 = n00 - 2 * (__popc(s00 ^ w) - __popc(w & i00));
                int v1 = n01 - 2 * (__popc(s01 ^ w) - __popc(w & i01));
                int v2 = n10 - 2 * (__popc(s10 ^ w) - __popc(w & i10));
                int v3 = n11 - 2 * (__popc(s11 ^ w) - __popc(w & i11));
                int vm = max(max(v0, v1), max(v2, v3));
                word |= (uint32_t)(vm >= s_ic1[c]) << c;
            }
        }
        s_H1[im][pi + 1][pj + 1] = word;
    }
    __syncthreads();

    // ---- conv2: wave per image; lane = oc; C[4][16] register window ----
    {
        const int im = wid;
        uint32_t wv[9];
#pragma unroll
        for (int k = 0; k < 9; ++k) wv[k] = s_W2t[k][lane];
        int ic2 = s_ic2[lane];
        int sth2 = (288 - ic2) >> 1;
        int pc0 = __popc(wv[0]), pc2 = __popc(wv[2]);
        int pc6 = __popc(wv[6]), pc8 = __popc(wv[8]);
        int topc = pc0 + __popc(wv[1]) + pc2;
        int botc = pc6 + __popc(wv[7]) + pc8;
        int lefc = pc0 + __popc(wv[3]) + pc6;
        int rigc = pc2 + __popc(wv[5]) + pc8;
        const uint32_t* plane = &s_H1[im][0][0];

        for (int pi = 0; pi < 7; ++pi) {
            uint32_t C[4][16];
#pragma unroll
            for (int r = 0; r < 4; ++r) {
                const uint32_t* rp = &plane[(2 * pi + r) * 16];
                *(uint4*)&C[r][0]  = *(const uint4*)&rp[0];
                *(uint4*)&C[r][4]  = *(const uint4*)&rp[4];
                *(uint4*)&C[r][8]  = *(const uint4*)&rp[8];
                *(uint4*)&C[r][12] = *(const uint4*)&rp[12];
            }
            const int rT = (pi == 0), rB = (pi == 6);
#pragma unroll
            for (int pj = 0; pj < 7; ++pj) {
                int S00 = 0, S01 = 0, S10 = 0, S11 = 0;
#pragma unroll
                for (int kh = 0; kh < 3; ++kh)
#pragma unroll
                    for (int kw = 0; kw < 3; ++kw) {
                        uint32_t ww = wv[kh * 3 + kw];
                        S00 += __popc(C[kh][2 * pj + kw] ^ ww);
                        S01 += __popc(C[kh][2 * pj + 1 + kw] ^ ww);
                        S10 += __popc(C[kh + 1][2 * pj + kw] ^ ww);
                        S11 += __popc(C[kh + 1][2 * pj + 1 + kw] ^ ww);
                    }
                int pred;
                if (pj >= 1 && pj <= 5) {
                    if (!rT && !rB) {
                        int Sm = min(min(S00, S01), min(S10, S11));
                        pred = (Sm <= sth2);
                    } else if (rT) {
                        int v0 = 192 - 2 * (S00 - topc);
                        int v1 = 192 - 2 * (S01 - topc);
                        int v2 = 288 - 2 * S10;
                        int v3 = 288 - 2 * S11;
                        pred = (max(max(v0, v1), max(v2, v3)) >= ic2);
                    } else {
                        int v0 = 288 - 2 * S00;
                        int v1 = 288 - 2 * S01;
                        int v2 = 192 - 2 * (S10 - botc);
                        int v3 = 192 - 2 * (S11 - botc);
                        pred = (max(max(v0, v1), max(v2, v3)) >= ic2);
                    }
                } else {
                    const int cL = (pj == 0), cR = (pj == 6);
                    int v0, v1, v2, v3;
                    { int rI = rT, cI = cL;
                      int corr = (rI ? topc : 0) + (cI ? lefc : 0) - ((rI & cI) ? pc0 : 0);
                      int nv = 32 * (9 - 3 * rI - 3 * cI + (rI & cI));
                      v0 = nv - 2 * (S00 - corr); }
                    { int rI = rT, cI = cR;
                      int corr = (rI ? topc : 0) + (cI ? rigc : 0) - ((rI & cI) ? pc2 : 0);
                      int nv = 32 * (9 - 3 * rI - 3 * cI + (rI & cI));
                      v1 = nv - 2 * (S01 - corr); }
                    { int rI = rB, cI = cL;
                      int corr = (rI ? botc : 0) + (cI ? lefc : 0) - ((rI & cI) ? pc6 : 0);
                      int nv = 32 * (9 - 3 * rI - 3 * cI + (rI & cI));
                      v2 = nv - 2 * (S10 - corr); }
                    { int rI = rB, cI = cR;
                      int corr = (rI ? botc : 0) + (cI ? rigc : 0) - ((rI & cI) ? pc8 : 0);
                      int nv = 32 * (9 - 3 * rI - 3 * cI + (rI & cI));
                      v3 = nv - 2 * (S11 - corr); }
                    pred = (max(max(v0, v1), max(v2, v3)) >= ic2);
                }
                unsigned long long m = __ballot(pred);
                if (lane == 0)
                    *(uint2*)&s_H2[im][pi + 1][pj + 1][0] =
                        make_uint2((uint32_t)m, (uint32_t)(m >> 32));
            }
        }
    }
    __syncthreads();

    // ---- conv3: lane = (oc 0..15, im 0..3); 49 pos over 4 waves ----
    {
        int oc = lane & 15, im = lane >> 4;
        uint32_t w[18];
#pragma unroll
        for (int k = 0; k < 18; ++k) w[k] = s_W3t[k][oc];
        float bias3 = s_b3[oc];
        int pc[9];
#pragma unroll
        for (int k = 0; k < 9; ++k) pc[k] = __popc(w[2 * k]) + __popc(w[2 * k + 1]);
        int topc = pc[0] + pc[1] + pc[2], botc = pc[6] + pc[7] + pc[8];
        int lefc = pc[0] + pc[3] + pc[6], rigc = pc[2] + pc[5] + pc[8];

        for (int pos = wid; pos < 49; pos += 4) {
            int pi = pos / 7, pj = pos - pi * 7;
            int S = 0;
#pragma unroll
            for (int kh = 0; kh < 3; ++kh)
#pragma unroll
                for (int kw = 0; kw < 3; ++kw) {
                    uint2 cc = *(const uint2*)&s_H2[im][pi + kh][pj + kw][0];
                    int k = kh * 3 + kw;
                    S += __popc(cc.x ^ w[2 * k]) + __popc(cc.y ^ w[2 * k + 1]);
                }
            int v;
            if (pi >= 1 && pi <= 5 && pj >= 1 && pj <= 5) {
                v = 576 - 2 * S;
            } else {
                int rT = (pi == 0), rB = (pi == 6), cL = (pj == 0), cR = (pj == 6);
                int rA = rT | rB, cA = cL | cR;
                int corr = (rT ? topc : 0) + (rB ? botc : 0) +
                           (cL ? lefc : 0) + (cR ? rigc : 0);
                if (rT & cL) corr -= pc[0];
                if (rT & cR) corr -= pc[2];
                if (rB & cL) corr -= pc[6];
                if (rB & cR) corr -= pc[8];
                int nInv = 3 * rA + 3 * cA - (rA & cA);
                v = 64 * (9 - nInv) - 2 * (S - corr);
            }
            float h = fmaxf((float)v + bias3, 0.f);
            h3T[(oc * 49 + pos) * 4096 + img0 + im] = h;
        }
    }
}

// ---------------- FC1: [4096x800]x[800x256], split-K=4, 8x8 tiles ----------
// block 64 img x 128 n, 128 threads, KC=40, 5 chunks (K/4 = 200)
__global__ __launch_bounds__(128, 2) void fc1_gemm(
    const float* __restrict__ aT, const float* __restrict__ bT,
    float* __restrict__ p0, float* __restrict__ pext, int bufmode) {
    __shared__ __align__(16) float As[40][64];
    __shared__ __align__(16) float Bs[40][128];
    const int t = threadIdx.x;
    const int img0 = blockIdx.x * 64;
    const int n0 = blockIdx.y * 128;
    const int z = blockIdx.z;
    const int k0 = z * 200;
    const int tx = t & 15, ty = t >> 4;   // tx: n-group 0..15, ty: img-group 0..7
    float acc[8][8] = {{0.f}};

    for (int ch = 0; ch < 5; ++ch) {
        int kb = k0 + ch * 40;
#pragma unroll
        for (int s = 0; s < 5; ++s) {      // A: 640 float4s
            int fid = t + s * 128;
            int kk = fid >> 4, c4 = (fid & 15) * 4;
            *(float4*)&As[kk][c4] = *(const float4*)&aT[(kb + kk) * 4096 + img0 + c4];
        }
#pragma unroll
        for (int s = 0; s < 10; ++s) {     // B: 1280 float4s
            int fid = t + s * 128;
            int kk = fid >> 5, c4 = (fid & 31) * 4;
            *(float4*)&Bs[kk][c4] = *(const float4*)&bT[(kb + kk) * 256 + n0 + c4];
        }
        __syncthreads();
#pragma unroll 4
        for (int kk = 0; kk < 40; ++kk) {
            float4 a0 = *(const float4*)&As[kk][ty * 8];
            float4 a1 = *(const float4*)&As[kk][ty * 8 + 4];
            float4 b0 = *(const float4*)&Bs[kk][tx * 8];
            float4 b1 = *(const float4*)&Bs[kk][tx * 8 + 4];
            float av[8] = {a0.x, a0.y, a0.z, a0.w, a1.x, a1.y, a1.z, a1.w};
            float bv[8] = {b0.x, b0.y, b0.z, b0.w, b1.x, b1.y, b1.z, b1.w};
#pragma unroll
            for (int i = 0; i < 8; ++i)
#pragma unroll
                for (int j = 0; j < 8; ++j) acc[i][j] += av[i] * bv[j];
        }
        __syncthreads();
    }
    if (bufmode) {
        float* dst = (z == 0) ? p0 : pext + (size_t)(z - 1) * 1048576;
#pragma unroll
        for (int j = 0; j < 8; ++j) {
            float* d = &dst[(n0 + tx * 8 + j) * 4096 + img0 + ty * 8];
            float4 v0 = make_float4(acc[0][j], acc[1][j], acc[2][j], acc[3][j]);
            float4 v1 = make_float4(acc[4][j], acc[5][j], acc[6][j], acc[7][j]);
            *(float4*)&d[0] = v0;
            *(float4*)&d[4] = v1;
        }
    } else {
#pragma unroll
        for (int j = 0; j < 8; ++j) {
            float* d = &p0[(n0 + tx * 8 + j) * 4096 + img0 + ty * 8];
#pragma unroll
            for (int i = 0; i < 8; ++i) atomicAdd(&d[i], acc[i][j]);
        }
    }
}

// ---------------- FC2: [4096x256]x[256x128], split-K=2, 4x4 tiles ----------
// block 64 img x 64 n, 256 threads, KC=32, 4 chunks (K/2 = 128)
// A-staging reduces fc1 partials + bias + relu.
__global__ __launch_bounds__(256, 2) void fc2_gemm(
    const float* __restrict__ p0, const float* __restrict__ pext,
    const float* __restrict__ fc1_b,
    const float* __restrict__ bT,
    float* __restrict__ q0, float* __restrict__ qext, int bufmode) {
    __shared__ __align__(16) float As[32][64];
    __shared__ __align__(16) float Bs[32][64];
    const int t = threadIdx.x;
    const int img0 = blockIdx.x * 64;
    const int n0 = blockIdx.y * 64;
    const int z = blockIdx.z;
    const int k0 = z * 128;
    const int tx = t & 15, ty = t >> 4;
    float acc[4][4] = {{0.f}};

    for (int ch = 0; ch < 4; ++ch) {
        int kb = k0 + ch * 32;
        {
            int kk = t >> 3, c4 = (t & 7) * 8;  // 8 floats = 2 float4 per thread
            size_t off = (size_t)(kb + kk) * 4096 + img0 + c4;
            float4 v0 = *(const float4*)&p0[off];
            float4 v1 = *(const float4*)&p0[off + 4];
            if (bufmode) {
#pragma unroll
                for (int s = 0; s < 3; ++s) {
                    const float* pp = pext + (size_t)s * 1048576;
                    float4 u0 = *(const float4*)&pp[off];
                    float4 u1 = *(const float4*)&pp[off + 4];
                    v0.x += u0.x; v0.y += u0.y; v0.z += u0.z; v0.w += u0.w;
                    v1.x += u1.x; v1.y += u1.y; v1.z += u1.z; v1.w += u1.w;
                }
            }
            float bb = fc1_b[kb + kk];
            v0.x = fmaxf(v0.x + bb, 0.f); v0.y = fmaxf(v0.y + bb, 0.f);
            v0.z = fmaxf(v0.z + bb, 0.f); v0.w = fmaxf(v0.w + bb, 0.f);
            v1.x = fmaxf(v1.x + bb, 0.f); v1.y = fmaxf(v1.y + bb, 0.f);
            v1.z = fmaxf(v1.z + bb, 0.f); v1.w = fmaxf(v1.w + bb, 0.f);
            *(float4*)&As[kk][c4] = v0;
            *(float4*)&As[kk][c4 + 4] = v1;
            *(float4*)&Bs[kk][c4] = *(const float4*)&bT[(kb + kk) * 128 + n0 + c4];
            *(float4*)&Bs[kk][c4 + 4] = *(const float4*)&bT[(kb + kk) * 128 + n0 + c4 + 4];
        }
        __syncthreads();
#pragma unroll 8
        for (int kk = 0; kk < 32; ++kk) {
            float4 a = *(const float4*)&As[kk][ty * 4];
            float4 b = *(const float4*)&Bs[kk][tx * 4];
            float av[4] = {a.x, a.y, a.z, a.w};
            float bv[4] = {b.x, b.y, b.z, b.w};
#pragma unroll
            for (int i = 0; i < 4; ++i)
#pragma unroll
                for (int j = 0; j < 4; ++j) acc[i][j] += av[i] * bv[j];
        }
        __syncthreads();
    }
    if (bufmode) {
        float* dst = (z == 0) ? q0 : qext;
#pragma unroll
        for (int j = 0; j < 4; ++j) {
            float4 v = make_float4(acc[0][j], acc[1][j], acc[2][j], acc[3][j]);
            *(float4*)&dst[(n0 + tx * 4 + j) * 4096 + img0 + ty * 4] = v;
        }
    } else {
#pragma unroll
        for (int j = 0; j < 4; ++j) {
            float* d = &q0[(n0 + tx * 4 + j) * 4096 + img0 + ty * 4];
#pragma unroll
            for (int i = 0; i < 4; ++i) atomicAdd(&d[i], acc[i][j]);
        }
    }
}

// ---------------- FC3: reduce h2 partials + bias + relu, then GEMV ---------
__global__ __launch_bounds__(256) void fc3_gemm(
    const float* __restrict__ q0, const float* __restrict__ qext,
    const float* __restrict__ fc2_b,
    const float* __restrict__ w, const float* __restrict__ bias,
    float* __restrict__ out, int bufmode) {
    int id = blockIdx.x * 256 + threadIdx.x;   // 40960
    int n = id >> 12, img = id & 4095;
    const float* wr = w + n * 128;
    float a0 = 0.f, a1 = 0.f;
#pragma unroll 8
    for (int k = 0; k < 128; k += 2) {
        float v0 = q0[(k + 0) * 4096 + img];
        float v1 = q0[(k + 1) * 4096 + img];
        if (bufmode) {
            v0 += qext[(k + 0) * 4096 + img];
            v1 += qext[(k + 1) * 4096 + img];
        }
        v0 = fmaxf(v0 + fc2_b[k], 0.f);
        v1 = fmaxf(v1 + fc2_b[k + 1], 0.f);
        a0 += v0 * wr[k];
        a1 += v1 * wr[k + 1];
    }
    out[img * 10 + n] = a0 + a1 + bias[n];
}

extern "C" void kernel_launch(void* const* d_in, const int* in_sizes, int n_in,
                              void* d_out, int out_size, void* d_ws, size_t ws_size,
                              hipStream_t stream) {
    const float* x     = (const float*)d_in[0];
    const float* w1    = (const float*)d_in[1];
    const float* b1    = (const float*)d_in[2];
    const float* w2    = (const float*)d_in[3];
    const float* b2    = (const float*)d_in[4];
    const float* w3    = (const float*)d_in[5];
    const float* b3    = (const float*)d_in[6];
    const float* fc1_w = (const float*)d_in[7];
    const float* fc1_b = (const float*)d_in[8];
    const float* fc2_w = (const float*)d_in[9];
    const float* fc2_b = (const float*)d_in[10];
    const float* fc3_w = (const float*)d_in[11];
    const float* fc3_b = (const float*)d_in[12];
    float* out = (float*)d_out;

    const int B = in_sizes[0] / 784;  // 4096
    char* ws = (char*)d_ws;
    uint32_t* pw = (uint32_t*)(ws + OFF_PW);
    float* w1T = (float*)(ws + OFF_W1T);
    float* w2T = (float*)(ws + OFF_W2T);
    float* h3T = (float*)(ws + OFF_H3T);
    float* h1p0 = (float*)(ws + OFF_H1T);
    float* h2p0 = (float*)(ws + OFF_H2T);
    const int bufmode = (ws_size >= WS_NEED_EXT) ? 1 : 0;
    float* h1ext = bufmode ? (float*)(ws + OFF_H1EXT) : h1p0;
    float* h2ext = bufmode ? (float*)(ws + OFF_H2EXT) : h2p0;

    if (!bufmode) {
        hipMemsetAsync(h1p0, 0, 4194304, stream);
        hipMemsetAsync(h2p0, 0, 2097152, stream);
    }
    hipLaunchKernelGGL(prep, dim3(1188), dim3(256), 0, stream,
                       w1, w2, w3, fc1_w, fc2_w, pw, w1T, w2T, h3T);
    hipLaunchKernelGGL(conv_stack, dim3(B / 4), dim3(256), 0, stream,
                       x, b1, b2, b3, pw, h3T);
    hipLaunchKernelGGL(fc1_gemm, dim3(B / 64, 2, 4), dim3(128), 0, stream,
                       h3T, w1T, h1p0, h1ext, bufmode);
    hipLaunchKernelGGL(fc2_gemm, dim3(B / 64, 2, 2), dim3(256), 0, stream,
                       h1p0, h1ext, fc1_b, w2T, h2p0, h2ext, bufmode);
    hipLaunchKernelGGL(fc3_gemm, dim3(B * 10 / 256), dim3(256), 0, stream,
                       h2p0, h2ext, fc2_b, fc3_w, fc3_b, out, bufmode);
}